// Round 8
// baseline (143.816 us; speedup 1.0000x reference)
//
#include <hip/hip_runtime.h>
#include <hip/hip_bf16.h>
#include <math.h>

#define B 4
#define S 2048
#define E 1024
#define A 128
#define CHUNK 256          // keys per split-K chunk
#define NCHMAX 8           // S / CHUNK

typedef __attribute__((ext_vector_type(4))) short shortx4;  // 4 bf16 (2 VGPRs)
typedef __attribute__((ext_vector_type(8))) short short8;   // 8 bf16 (4 VGPRs)
typedef __attribute__((ext_vector_type(4))) float floatx4;  // MFMA C/D

// 16x16x16 bf16 MFMA (K=16): A/B are 4 bf16. Carried forward from gfx90a.
#if defined(__has_builtin)
#if __has_builtin(__builtin_amdgcn_mfma_f32_16x16x16bf16_1k)
#define MFMA16(Av, Bv, Cv) __builtin_amdgcn_mfma_f32_16x16x16bf16_1k((Av), (Bv), (Cv), 0, 0, 0)
#endif
#endif
#ifndef MFMA16
static __device__ __forceinline__ floatx4 mfma16_asm(shortx4 a, shortx4 b, floatx4 c) {
  floatx4 d;
  asm volatile("v_mfma_f32_16x16x16_bf16 %0, %1, %2, %3"
               : "=v"(d) : "v"(a), "v"(b), "v"(c));
  return d;
}
#define MFMA16(Av, Bv, Cv) mfma16_asm((Av), (Bv), (Cv))
#endif

// fp32 -> bf16 scalar (RNE)
static __device__ __forceinline__ short f2bf(float f) {
  union { float f; unsigned u; } c;
  c.f = f;
  unsigned r = (c.u + 0x7fffu + ((c.u >> 16) & 1u)) >> 16;
  return (short)r;
}
// packed pair: 2 fp32 -> 2 bf16 in one uint (v_cvt_pk_bf16_f32)
static __device__ __forceinline__ unsigned f2bf2(float x, float y) {
  __hip_bfloat162 h = __float22bfloat162_rn(float2{x, y});
  union { __hip_bfloat162 h; unsigned u; } c;
  c.h = h;
  return c.u;
}

// ---------------------------------------------------------------------------
// One-shot W conversion: Wq/Wk/Wv fp32 [A][E] -> bf16, so proj_gemm doesn't
// re-convert W in every block (was 256 pk-cvts/thread/block).
// ---------------------------------------------------------------------------
__global__ __launch_bounds__(256) void wconv(
    const float* __restrict__ Wq,
    const float* __restrict__ Wk,
    const float* __restrict__ Wv,
    short* __restrict__ Wbf) {       // [3][A][E]
  const int which = blockIdx.y;
  const float* Wp = (which == 0) ? Wq : (which == 1) ? Wk : Wv;
  short* o = Wbf + (size_t)which * A * E;
  const int f = blockIdx.x * 256 + threadIdx.x;   // float4 slot, A*E/4 total
  const float4 v = *(const float4*)&Wp[(size_t)f * 4];
  uint2 p; p.x = f2bf2(v.x, v.y); p.y = f2bf2(v.z, v.w);
  *(uint2*)&o[(size_t)f * 4] = p;
}

// ---------------------------------------------------------------------------
// Projection GEMM: C[8192,128] = X.W^T for q/k/v. W already bf16.
// ---------------------------------------------------------------------------
#define PJ 72
__global__ __launch_bounds__(256) void proj_gemm(
    const float* __restrict__ X,
    const short* __restrict__ Wbf,   // [3][A][E] bf16
    short* __restrict__ Qbf,
    short* __restrict__ Kbf,
    short* __restrict__ Vt) {
  __shared__ short As[64 * PJ];
  __shared__ short Bs[128 * PJ];

  const int m0 = blockIdx.x * 64;
  const int which = blockIdx.y;
  const short* Wpb = Wbf + (size_t)which * A * E;

  const int tid = threadIdx.x;
  const int wave = tid >> 6;
  const int lane = tid & 63;
  const int mh = wave & 1;
  const int nh = wave >> 1;
  const int l16 = lane & 15;
  const int quad = lane >> 4;

  floatx4 acc[2][4] = {};

  for (int k0 = 0; k0 < E; k0 += 64) {
    // ---- stage A: X[m0..+63][k0..+63] fp32 -> bf16 (converted once/elem) ----
#pragma unroll
    for (int i = 0; i < 4; ++i) {
      const int f = tid + i * 256;
      const int row = f >> 4, c4 = f & 15;
      const float4 v = *(const float4*)&X[(size_t)(m0 + row) * E + k0 + c4 * 4];
      uint2 p; p.x = f2bf2(v.x, v.y); p.y = f2bf2(v.z, v.w);
      *(uint2*)&As[row * PJ + c4 * 4] = p;
    }
    // ---- stage B: W bf16 straight copy, no VALU convert ----
#pragma unroll
    for (int i = 0; i < 4; ++i) {
      const int f = tid + i * 256;          // 1024 slots of 8 shorts
      const int row = f >> 3, c8 = f & 7;
      *(short8*)&Bs[row * PJ + c8 * 8] =
          *(const short8*)&Wpb[(size_t)row * E + k0 + c8 * 8];
    }
    __syncthreads();

    short8 afr[2][2], bfr[4][2];
#pragma unroll
    for (int ms = 0; ms < 2; ++ms)
#pragma unroll
      for (int ks = 0; ks < 2; ++ks)
        afr[ms][ks] = *(const short8*)&As[(mh * 32 + ms * 16 + l16) * PJ + ks * 32 + quad * 8];
#pragma unroll
    for (int nt = 0; nt < 4; ++nt)
#pragma unroll
      for (int ks = 0; ks < 2; ++ks)
        bfr[nt][ks] = *(const short8*)&Bs[(nh * 64 + nt * 16 + l16) * PJ + ks * 32 + quad * 8];

#pragma unroll
    for (int ms = 0; ms < 2; ++ms)
#pragma unroll
      for (int nt = 0; nt < 4; ++nt)
#pragma unroll
        for (int ks = 0; ks < 2; ++ks)
          acc[ms][nt] = __builtin_amdgcn_mfma_f32_16x16x32_bf16(
              afr[ms][ks], bfr[nt][ks], acc[ms][nt], 0, 0, 0);
    __syncthreads();
  }

  const float qscale = 0.08838834764831845f;  // 1/sqrt(128)
#pragma unroll
  for (int ms = 0; ms < 2; ++ms) {
#pragma unroll
    for (int nt = 0; nt < 4; ++nt) {
      const int n = nh * 64 + nt * 16 + l16;
      const int mbase = m0 + mh * 32 + ms * 16 + quad * 4;   // + r
      if (which == 2) {
        const int b = mbase >> 11, s = mbase & (S - 1);
        short4 p;
        p.x = f2bf(acc[ms][nt][0]); p.y = f2bf(acc[ms][nt][1]);
        p.z = f2bf(acc[ms][nt][2]); p.w = f2bf(acc[ms][nt][3]);
        *(short4*)&Vt[((size_t)b * A + n) * S + s] = p;
      } else {
        short* Outp = (which == 0) ? Qbf : Kbf;
        const float sc = (which == 0) ? qscale : 1.0f;
#pragma unroll
        for (int r = 0; r < 4; ++r)
          Outp[(size_t)(mbase + r) * A + n] = f2bf(acc[ms][nt][r] * sc);
      }
    }
  }
}

// ---------------------------------------------------------------------------
// Flash-causal attention, operand-swapped (no P LDS round-trip):
//   S^T = mfma_16x16x32(A=K, B=Q)  -> C/D: qrow = l16, key = quad*4 + r
//   p = exp(s) masked (no max-sub; scores bounded ~|3|)
//   P packs from score regs directly into the 16x16x16 PV B-operand
//     (B[n=qrow=l16][k=key=quad*4+j] == score regs 0..3 bf16-packed)
//   O^T += mfma_16x16x16(A=V^T from Vs[a][key], B=P)
//     C/D: qrow = l16, a = quad*4 + r  -> float4 Opart stores.
// Split-K: 128 q-tiles x 8 chunks of 256 keys; plain-sum partials.
// ---------------------------------------------------------------------------
#define LK 132   // Ks row stride (shorts)
#define LV 68    // Vs row stride (shorts)
__global__ __launch_bounds__(256) void attn_part(
    const short* __restrict__ Qbf,
    const short* __restrict__ Kbf,
    const short* __restrict__ Vt,
    float* __restrict__ Opart,    // [128*8][64][128]
    float* __restrict__ Lpart) {  // [128*8][64]
  __shared__ short Ks[64 * LK];       // [key][a]
  __shared__ short Vs[128 * LV];      // [a][key]

  const int rev = (int)gridDim.x - 1 - (int)blockIdx.x;   // heavy-first
  const int qt = rev >> 3;            // 0..127
  const int chunk = rev & 7;
  const int b = qt >> 5;
  const int q0 = (qt & 31) << 6;
  const int nk = q0 + 64;             // causal limit
  const int kstart = chunk * CHUNK;
  if (kstart >= nk) return;
  const int kend = min(kstart + CHUNK, nk);

  const int tid = threadIdx.x;
  const int wave = tid >> 6;
  const int lane = tid & 63;
  const int l16 = lane & 15;
  const int quad = lane >> 4;

  const int qrow = q0 + wave * 16 + l16;   // this lane's query row (B-operand n)

  // Q B-fragments: B[n=qrow][k=ks*32+quad*8 ..] — same read pattern as A-frag
  short8 qfr[4];
  {
    const size_t qr = (size_t)(b * S + qrow);
#pragma unroll
    for (int ks = 0; ks < 4; ++ks)
      qfr[ks] = *(const short8*)&Qbf[qr * A + ks * 32 + quad * 8];
  }

  float l_acc = 0.f;          // per-lane partial of l[qrow] (keys = quad*4+r slices)
  floatx4 oaccT[8] = {};      // O^T: [a-tile at][r: a=at*16+quad*4+r], col q=l16

  const short* Kbase = Kbf + (size_t)b * S * A;
  const short* Vbase = Vt + (size_t)b * A * S;

  for (int j0 = kstart; j0 < kend; j0 += 64) {
    // ---- stage K-tile [64 keys][128 a] ----
#pragma unroll
    for (int i = 0; i < 4; ++i) {
      const int f = tid + i * 256;
      const int row = f >> 4, c8 = f & 15;
      *(short8*)&Ks[row * LK + c8 * 8] =
          *(const short8*)&Kbase[(size_t)(j0 + row) * A + c8 * 8];
    }
    // ---- stage V-tile [128 a][64 keys] ----
#pragma unroll
    for (int i = 0; i < 4; ++i) {
      const int f = tid + i * 256;
      const int ar = f >> 3, c8 = f & 7;
      *(short8*)&Vs[ar * LV + c8 * 8] =
          *(const short8*)&Vbase[(size_t)ar * S + j0 + c8 * 8];
    }
    __syncthreads();

#pragma unroll
    for (int nt = 0; nt < 4; ++nt) {
      // ---- S^T tile: m=key (nt*16+l16 rows of Ks), n=qrow ----
      floatx4 st = {};
#pragma unroll
      for (int ks = 0; ks < 4; ++ks) {
        const short8 kfr = *(const short8*)&Ks[(nt * 16 + l16) * LK + ks * 32 + quad * 8];
        st = __builtin_amdgcn_mfma_f32_16x16x32_bf16(kfr, qfr[ks], st, 0, 0, 0);
      }
      // ---- mask + exp; pack P into PV B-fragment (keys quad*4+0..3) ----
      float pr[4];
#pragma unroll
      for (int r = 0; r < 4; ++r) {
        const int key = j0 + nt * 16 + quad * 4 + r;
        const float p = (key > qrow) ? 0.f : __expf(st[r]);
        pr[r] = p;
        l_acc += p;
      }
      union { uint2 u; shortx4 s; } pk;
      pk.u.x = f2bf2(pr[0], pr[1]);
      pk.u.y = f2bf2(pr[2], pr[3]);
      const shortx4 pfrB = pk.s;

      // ---- O^T += V^T . P : A[m=a][k=key] from Vs rows, K=16 ----
#pragma unroll
      for (int at = 0; at < 8; ++at) {
        const shortx4 vfr = *(const shortx4*)&Vs[(at * 16 + l16) * LV + nt * 16 + quad * 4];
        oaccT[at] = MFMA16(vfr, pfrB, oaccT[at]);
      }
    }
    __syncthreads();   // protect Ks/Vs restage
  }

  // ---- epilogue ----
  // l: reduce across the 4 quads (lanes sharing l16)
  l_acc += __shfl_xor(l_acc, 16);
  l_acc += __shfl_xor(l_acc, 32);

  const int slot = qt * NCHMAX + chunk;
  float* op = Opart + (size_t)slot * 64 * 128;
  const int lr = wave * 16 + l16;     // q-row within tile
#pragma unroll
  for (int at = 0; at < 8; ++at) {
    float4 v;
    v.x = oaccT[at][0]; v.y = oaccT[at][1];
    v.z = oaccT[at][2]; v.w = oaccT[at][3];
    *(float4*)&op[(size_t)lr * 128 + at * 16 + quad * 4] = v;
  }
  if (quad == 0) Lpart[slot * 64 + lr] = l_acc;
}

// ---------------------------------------------------------------------------
// Phase B: plain-sum combine of <=8 chunk partials per row, then normalize.
// ---------------------------------------------------------------------------
__global__ __launch_bounds__(256) void attn_reduce(
    const float* __restrict__ Opart,
    const float* __restrict__ Lpart,
    float* __restrict__ Out) {
  const int qt = blockIdx.x;          // 0..127
  const int b = qt >> 5;
  const int q0 = (qt & 31) << 6;
  const int nch = (q0 + 64 + CHUNK - 1) / CHUNK;

  const int tid = threadIdx.x;
  const int lr = tid >> 2;            // 0..63
  const int c0 = (tid & 3) * 32;

  float ltot = 0.f;
  for (int c = 0; c < nch; ++c) ltot += Lpart[(qt * NCHMAX + c) * 64 + lr];
  const float inv = 1.f / ltot;

  float4 acc[8] = {};
  for (int c = 0; c < nch; ++c) {
    const float4* op = (const float4*)
        (Opart + ((size_t)(qt * NCHMAX + c) * 64 + lr) * 128 + c0);
#pragma unroll
    for (int i = 0; i < 8; ++i) {
      const float4 v = op[i];
      acc[i].x += v.x; acc[i].y += v.y; acc[i].z += v.z; acc[i].w += v.w;
    }
  }

  float4* o = (float4*)(Out + (size_t)(b * S + q0 + lr) * A + c0);
#pragma unroll
  for (int i = 0; i < 8; ++i) {
    float4 v = acc[i];
    v.x *= inv; v.y *= inv; v.z *= inv; v.w *= inv;
    o[i] = v;
  }
}

extern "C" void kernel_launch(void* const* d_in, const int* in_sizes, int n_in,
                              void* d_out, int out_size, void* d_ws, size_t ws_size,
                              hipStream_t stream) {
  const float* X  = (const float*)d_in[0];  // embedded [B,S,E]
  const float* Wk = (const float*)d_in[1];  // [A,E]
  const float* Wq = (const float*)d_in[2];
  const float* Wv = (const float*)d_in[3];
  float* Out = (float*)d_out;               // [B,S,A]

  const size_t qkv_elems = (size_t)B * S * A;   // 1M elems, bf16 -> 2MB each
  short* Qbf = (short*)d_ws;
  short* Kbf = Qbf + qkv_elems;
  short* Vt  = Kbf + qkv_elems;
  float* Opart = (float*)(Vt + qkv_elems);            // 1024*64*128*4 = 33.6MB
  float* Lpart = Opart + (size_t)1024 * 64 * 128;     // 1024*64*4
  short* Wbf = (short*)(Lpart + (size_t)1024 * 64);   // 3*128*1024*2 = 768KB

  wconv<<<dim3(A * E / 4 / 256, 3), 256, 0, stream>>>(Wq, Wk, Wv, Wbf);
  dim3 pgrid(B * S / 64, 3);
  proj_gemm<<<pgrid, 256, 0, stream>>>(X, Wbf, Qbf, Kbf, Vt);
  attn_part<<<(B * S / 64) * NCHMAX, 256, 0, stream>>>(Qbf, Kbf, Vt, Opart, Lpart);
  attn_reduce<<<B * S / 64, 256, 0, stream>>>(Opart, Lpart, Out);
}

// Round 9
// 131.512 us; speedup vs baseline: 1.0936x; 1.0936x over previous
//
#include <hip/hip_runtime.h>
#include <hip/hip_bf16.h>
#include <math.h>

#define B 4
#define S 2048
#define E 1024
#define A 128
#define CHUNK 256          // keys per split-K chunk
#define NCHMAX 8           // S / CHUNK

typedef __attribute__((ext_vector_type(8))) short short8;   // 8 bf16 (4 VGPRs)
typedef __attribute__((ext_vector_type(4))) float floatx4;  // MFMA C/D

// fp32 -> bf16 scalar (RNE)
static __device__ __forceinline__ short f2bf(float f) {
  union { float f; unsigned u; } c;
  c.f = f;
  unsigned r = (c.u + 0x7fffu + ((c.u >> 16) & 1u)) >> 16;
  return (short)r;
}
// packed pair: 2 fp32 -> 2 bf16 in one uint (v_cvt_pk_bf16_f32)
static __device__ __forceinline__ unsigned f2bf2(float x, float y) {
  __hip_bfloat162 h = __float22bfloat162_rn(float2{x, y});
  union { __hip_bfloat162 h; unsigned u; } c;
  c.h = h;
  return c.u;
}

// ---------------------------------------------------------------------------
// One-shot W conversion: Wq/Wk/Wv fp32 [A][E] -> bf16.
// ---------------------------------------------------------------------------
__global__ __launch_bounds__(256) void wconv(
    const float* __restrict__ Wq,
    const float* __restrict__ Wk,
    const float* __restrict__ Wv,
    short* __restrict__ Wbf) {       // [3][A][E]
  const int which = blockIdx.y;
  const float* Wp = (which == 0) ? Wq : (which == 1) ? Wk : Wv;
  short* o = Wbf + (size_t)which * A * E;
  const int f = blockIdx.x * 256 + threadIdx.x;   // float4 slot
  const float4 v = *(const float4*)&Wp[(size_t)f * 4];
  uint2 p; p.x = f2bf2(v.x, v.y); p.y = f2bf2(v.z, v.w);
  *(uint2*)&o[(size_t)f * 4] = p;
}

// ---------------------------------------------------------------------------
// Projection GEMM with register-prefetch pipelining (distance 1):
// loads for k-tile i+1 are issued right after the staging barrier of tile i
// and only waited on at tile i+1's ds_write — global latency overlaps MFMA.
// ---------------------------------------------------------------------------
#define PJ 72
__global__ __launch_bounds__(256) void proj_gemm(
    const float* __restrict__ X,
    const short* __restrict__ Wbf,   // [3][A][E] bf16
    short* __restrict__ Qbf,
    short* __restrict__ Kbf,
    short* __restrict__ Vt) {
  __shared__ short As[64 * PJ];
  __shared__ short Bs[128 * PJ];

  const int m0 = blockIdx.x * 64;
  const int which = blockIdx.y;
  const short* Wpb = Wbf + (size_t)which * A * E;

  const int tid = threadIdx.x;
  const int wave = tid >> 6;
  const int lane = tid & 63;
  const int mh = wave & 1;
  const int nh = wave >> 1;
  const int l16 = lane & 15;
  const int quad = lane >> 4;

  // staging slot geometry (constant per thread)
  int arow[4], ac4[4], brow[4], bc8[4];
#pragma unroll
  for (int i = 0; i < 4; ++i) {
    const int fa = tid + i * 256;          // 1024 float4 slots (64x16)
    arow[i] = fa >> 4; ac4[i] = fa & 15;
    const int fb = tid + i * 256;          // 1024 short8 slots (128x8)
    brow[i] = fb >> 3; bc8[i] = fb & 7;
  }

  floatx4 acc[2][4] = {};
  float4 aplf[4];
  short8 bplf[4];

  // prologue: load k0 = 0
#pragma unroll
  for (int i = 0; i < 4; ++i) {
    aplf[i] = *(const float4*)&X[(size_t)(m0 + arow[i]) * E + ac4[i] * 4];
    bplf[i] = *(const short8*)&Wpb[(size_t)brow[i] * E + bc8[i] * 8];
  }

  for (int k0 = 0; k0 < E; k0 += 64) {
    __syncthreads();                 // prev iter's LDS consumers done
#pragma unroll
    for (int i = 0; i < 4; ++i) {
      uint2 p; p.x = f2bf2(aplf[i].x, aplf[i].y); p.y = f2bf2(aplf[i].z, aplf[i].w);
      *(uint2*)&As[arow[i] * PJ + ac4[i] * 4] = p;
      *(short8*)&Bs[brow[i] * PJ + bc8[i] * 8] = bplf[i];
    }
    __syncthreads();                 // staging visible

    // prefetch next k-tile (no wait until next iter's ds_write)
    if (k0 + 64 < E) {
#pragma unroll
      for (int i = 0; i < 4; ++i) {
        aplf[i] = *(const float4*)&X[(size_t)(m0 + arow[i]) * E + (k0 + 64) + ac4[i] * 4];
        bplf[i] = *(const short8*)&Wpb[(size_t)brow[i] * E + (k0 + 64) + bc8[i] * 8];
      }
    }

    short8 afr[2][2], bfr[4][2];
#pragma unroll
    for (int ms = 0; ms < 2; ++ms)
#pragma unroll
      for (int ks = 0; ks < 2; ++ks)
        afr[ms][ks] = *(const short8*)&As[(mh * 32 + ms * 16 + l16) * PJ + ks * 32 + quad * 8];
#pragma unroll
    for (int nt = 0; nt < 4; ++nt)
#pragma unroll
      for (int ks = 0; ks < 2; ++ks)
        bfr[nt][ks] = *(const short8*)&Bs[(nh * 64 + nt * 16 + l16) * PJ + ks * 32 + quad * 8];

#pragma unroll
    for (int ms = 0; ms < 2; ++ms)
#pragma unroll
      for (int nt = 0; nt < 4; ++nt)
#pragma unroll
        for (int ks = 0; ks < 2; ++ks)
          acc[ms][nt] = __builtin_amdgcn_mfma_f32_16x16x32_bf16(
              afr[ms][ks], bfr[nt][ks], acc[ms][nt], 0, 0, 0);
  }

  const float qscale = 0.08838834764831845f;  // 1/sqrt(128)
#pragma unroll
  for (int ms = 0; ms < 2; ++ms) {
#pragma unroll
    for (int nt = 0; nt < 4; ++nt) {
      const int n = nh * 64 + nt * 16 + l16;
      const int mbase = m0 + mh * 32 + ms * 16 + quad * 4;   // + r
      if (which == 2) {
        const int b = mbase >> 11, s = mbase & (S - 1);
        short4 p;
        p.x = f2bf(acc[ms][nt][0]); p.y = f2bf(acc[ms][nt][1]);
        p.z = f2bf(acc[ms][nt][2]); p.w = f2bf(acc[ms][nt][3]);
        *(short4*)&Vt[((size_t)b * A + n) * S + s] = p;
      } else {
        short* Outp = (which == 0) ? Qbf : Kbf;
        const float sc = (which == 0) ? qscale : 1.0f;
#pragma unroll
        for (int r = 0; r < 4; ++r)
          Outp[(size_t)(mbase + r) * A + n] = f2bf(acc[ms][nt][r] * sc);
      }
    }
  }
}

// ---------------------------------------------------------------------------
// Flash-causal attention, no max-subtraction (scores bounded ~|3|), split-K
// (128 q-tiles x 8 chunks of 256 keys), P via wave-private LDS transpose,
// register-prefetch pipelining of the K/V staging (distance 1).
// ---------------------------------------------------------------------------
#define LK 132   // Ks row stride (shorts)
#define LV 68    // Vs/Ps row stride (shorts)
__global__ __launch_bounds__(256) void attn_part(
    const short* __restrict__ Qbf,
    const short* __restrict__ Kbf,
    const short* __restrict__ Vt,
    float* __restrict__ Opart,    // [128*8][64][128]
    float* __restrict__ Lpart) {  // [128*8][64]
  __shared__ short Ks[64 * LK];       // [key][a]
  __shared__ short Vs[128 * LV];      // [a][key]
  __shared__ short Ps[4][16 * LV];    // per-wave [row][key]

  const int rev = (int)gridDim.x - 1 - (int)blockIdx.x;   // heavy-first
  const int qt = rev >> 3;            // 0..127
  const int chunk = rev & 7;
  const int b = qt >> 5;
  const int q0 = (qt & 31) << 6;
  const int nk = q0 + 64;             // causal limit
  const int kstart = chunk * CHUNK;
  if (kstart >= nk) return;
  const int kend = min(kstart + CHUNK, nk);

  const int tid = threadIdx.x;
  const int wave = tid >> 6;
  const int lane = tid & 63;
  const int l16 = lane & 15;
  const int quad = lane >> 4;

  // staging geometry
  int krow[4], kc8[4], vrow[4], vc8[4];
#pragma unroll
  for (int i = 0; i < 4; ++i) {
    const int f = tid + i * 256;
    krow[i] = f >> 4; kc8[i] = f & 15;    // 64 rows x 16 slots
    vrow[i] = f >> 3; vc8[i] = f & 7;     // 128 rows x 8 slots
  }

  // Q A-fragments
  short8 qfr[4];
  {
    const size_t qrow = (size_t)(b * S + q0 + wave * 16 + l16);
#pragma unroll
    for (int ks = 0; ks < 4; ++ks)
      qfr[ks] = *(const short8*)&Qbf[qrow * A + ks * 32 + quad * 8];
  }

  float l_acc[4] = {0.f, 0.f, 0.f, 0.f};
  floatx4 oacc[8] = {};

  const int myrow = q0 + wave * 16 + quad * 4;      // + r
  const short* Kbase = Kbf + (size_t)b * S * A;
  const short* Vbase = Vt + (size_t)b * A * S;

  short8 kplf[4], vplf[4];
  // prologue: load first tile
#pragma unroll
  for (int i = 0; i < 4; ++i) {
    kplf[i] = *(const short8*)&Kbase[(size_t)(kstart + krow[i]) * A + kc8[i] * 8];
    vplf[i] = *(const short8*)&Vbase[(size_t)vrow[i] * S + kstart + vc8[i] * 8];
  }

  for (int j0 = kstart; j0 < kend; j0 += 64) {
    __syncthreads();                 // prev iter's LDS consumers done
#pragma unroll
    for (int i = 0; i < 4; ++i) {
      *(short8*)&Ks[krow[i] * LK + kc8[i] * 8] = kplf[i];
      *(short8*)&Vs[vrow[i] * LV + vc8[i] * 8] = vplf[i];
    }
    __syncthreads();                 // staging visible

    // prefetch next tile (waited on at next iter's ds_write)
    if (j0 + 64 < kend) {
#pragma unroll
      for (int i = 0; i < 4; ++i) {
        kplf[i] = *(const short8*)&Kbase[(size_t)(j0 + 64 + krow[i]) * A + kc8[i] * 8];
        vplf[i] = *(const short8*)&Vbase[(size_t)vrow[i] * S + j0 + 64 + vc8[i] * 8];
      }
    }

    // ---- S = Q.K^T  (4 n-tiles of 16 keys) ----
    floatx4 sc[4];
#pragma unroll
    for (int nt = 0; nt < 4; ++nt) {
      floatx4 c = {};
#pragma unroll
      for (int ks = 0; ks < 4; ++ks) {
        const short8 bfr = *(const short8*)&Ks[(nt * 16 + l16) * LK + ks * 32 + quad * 8];
        c = __builtin_amdgcn_mfma_f32_16x16x32_bf16(qfr[ks], bfr, c, 0, 0, 0);
      }
      sc[nt] = c;
    }

    // ---- mask + exp (no max-sub), accumulate l ----
#pragma unroll
    for (int nt = 0; nt < 4; ++nt) {
      const int key = j0 + nt * 16 + l16;
#pragma unroll
      for (int r = 0; r < 4; ++r) {
        const float p = (key > myrow + r) ? 0.f : __expf(sc[nt][r]);
        sc[nt][r] = p;
        l_acc[r] += p;
      }
    }

    // ---- P -> wave-private LDS -> A-operand layout ----
#pragma unroll
    for (int nt = 0; nt < 4; ++nt)
#pragma unroll
      for (int r = 0; r < 4; ++r)
        Ps[wave][(quad * 4 + r) * LV + nt * 16 + l16] = f2bf(sc[nt][r]);

    short8 pfr[2];
#pragma unroll
    for (int ks = 0; ks < 2; ++ks)
      pfr[ks] = *(const short8*)&Ps[wave][l16 * LV + ks * 32 + quad * 8];

    // ---- O += P.V  (8 a-tiles x 2 k-steps of 32 keys) ----
#pragma unroll
    for (int nt = 0; nt < 8; ++nt) {
#pragma unroll
      for (int ks = 0; ks < 2; ++ks) {
        const short8 vfr = *(const short8*)&Vs[(nt * 16 + l16) * LV + ks * 32 + quad * 8];
        oacc[nt] = __builtin_amdgcn_mfma_f32_16x16x32_bf16(pfr[ks], vfr, oacc[nt], 0, 0, 0);
      }
    }
  }

  // ---- epilogue ----
  const int slot = qt * NCHMAX + chunk;
  float* op = Opart + (size_t)slot * 64 * 128;
  const int lr = wave * 16 + quad * 4;   // + r
#pragma unroll
  for (int nt = 0; nt < 8; ++nt)
#pragma unroll
    for (int r = 0; r < 4; ++r)
      op[(lr + r) * 128 + nt * 16 + l16] = oacc[nt][r];

#pragma unroll
  for (int r = 0; r < 4; ++r) {
    float l = l_acc[r];
    l += __shfl_xor(l, 1);
    l += __shfl_xor(l, 2);
    l += __shfl_xor(l, 4);
    l += __shfl_xor(l, 8);
    if (l16 == 0) Lpart[slot * 64 + lr + r] = l;
  }
}

// ---------------------------------------------------------------------------
// Phase B: plain-sum combine of <=8 chunk partials per row, then normalize.
// ---------------------------------------------------------------------------
__global__ __launch_bounds__(256) void attn_reduce(
    const float* __restrict__ Opart,
    const float* __restrict__ Lpart,
    float* __restrict__ Out) {
  const int qt = blockIdx.x;          // 0..127
  const int b = qt >> 5;
  const int q0 = (qt & 31) << 6;
  const int nch = (q0 + 64 + CHUNK - 1) / CHUNK;

  const int tid = threadIdx.x;
  const int lr = tid >> 2;            // 0..63
  const int c0 = (tid & 3) * 32;

  float ltot = 0.f;
  for (int c = 0; c < nch; ++c) ltot += Lpart[(qt * NCHMAX + c) * 64 + lr];
  const float inv = 1.f / ltot;

  float4 acc[8] = {};
  for (int c = 0; c < nch; ++c) {
    const float4* op = (const float4*)
        (Opart + ((size_t)(qt * NCHMAX + c) * 64 + lr) * 128 + c0);
#pragma unroll
    for (int i = 0; i < 8; ++i) {
      const float4 v = op[i];
      acc[i].x += v.x; acc[i].y += v.y; acc[i].z += v.z; acc[i].w += v.w;
    }
  }

  float4* o = (float4*)(Out + (size_t)(b * S + q0 + lr) * A + c0);
#pragma unroll
  for (int i = 0; i < 8; ++i) {
    float4 v = acc[i];
    v.x *= inv; v.y *= inv; v.z *= inv; v.w *= inv;
    o[i] = v;
  }
}

extern "C" void kernel_launch(void* const* d_in, const int* in_sizes, int n_in,
                              void* d_out, int out_size, void* d_ws, size_t ws_size,
                              hipStream_t stream) {
  const float* X  = (const float*)d_in[0];  // embedded [B,S,E]
  const float* Wk = (const float*)d_in[1];  // [A,E]
  const float* Wq = (const float*)d_in[2];
  const float* Wv = (const float*)d_in[3];
  float* Out = (float*)d_out;               // [B,S,A]

  const size_t qkv_elems = (size_t)B * S * A;   // 1M elems, bf16 -> 2MB each
  short* Qbf = (short*)d_ws;
  short* Kbf = Qbf + qkv_elems;
  short* Vt  = Kbf + qkv_elems;
  float* Opart = (float*)(Vt + qkv_elems);            // 1024*64*128*4 = 33.6MB
  float* Lpart = Opart + (size_t)1024 * 64 * 128;     // 1024*64*4
  short* Wbf = (short*)(Lpart + (size_t)1024 * 64);   // 3*128*1024*2 = 768KB

  wconv<<<dim3(A * E / 4 / 256, 3), 256, 0, stream>>>(Wq, Wk, Wv, Wbf);
  dim3 pgrid(B * S / 64, 3);
  proj_gemm<<<pgrid, 256, 0, stream>>>(X, Wbf, Qbf, Kbf, Vt);
  attn_part<<<(B * S / 64) * NCHMAX, 256, 0, stream>>>(Qbf, Kbf, Vt, Opart, Lpart);
  attn_reduce<<<B * S / 64, 256, 0, stream>>>(Opart, Lpart, Out);
}